// Round 9
// baseline (231.737 us; speedup 1.0000x reference)
//
#include <hip/hip_runtime.h>
#include <hip/hip_bf16.h>
#include <math.h>

#define B 64
#define S 2048
#define H 512
#define BMT 128

// workspace layout (floats)
#define QS_OFF 0                    // qs:     B*H
#define SC_OFF (B*H)                // scores: B*S
#define PC_OFF (B*H + B*S)          // pc:     B*NCHUNK*H  (Wt aliases this region, used before pc)
#define NCHUNK 32
#define CHUNK  64                   // S / NCHUNK

typedef __attribute__((ext_vector_type(8))) short short8;
typedef __attribute__((ext_vector_type(4))) float f32x4;

static __device__ __forceinline__ short f2bf(float f) {
    union { float f; unsigned u; } x; x.f = f;
    unsigned r = x.u + 0x7fffu + ((x.u >> 16) & 1u);   // RNE
    return (short)(r >> 16);
}

static __device__ __forceinline__ float ftanh(float x) {
    x = fminf(fmaxf(x, -30.f), 30.f);
    const float e = __builtin_amdgcn_exp2f(x * 2.8853900817779268f); // e^(2x)
    return (e - 1.f) * __builtin_amdgcn_rcpf(e + 1.f);
}

static __device__ __forceinline__ short8 cvt8(float4 a, float4 b) {
    union { short8 s; __hip_bfloat162 h[4]; } u;
    u.h[0] = __float22bfloat162_rn(make_float2(a.x, a.y));
    u.h[1] = __float22bfloat162_rn(make_float2(a.z, a.w));
    u.h[2] = __float22bfloat162_rn(make_float2(b.x, b.y));
    u.h[3] = __float22bfloat162_rn(make_float2(b.z, b.w));
    return u.s;
}

#define GLL16(g_, l_) __builtin_amdgcn_global_load_lds(                        \
    (const __attribute__((address_space(1))) void*)(g_),                      \
    (__attribute__((address_space(3))) void*)(l_), 16, 0, 0)

// ---------------- kernel 1: q_scores = query @ W_s (B,H) ----------------
__global__ __launch_bounds__(512) void qs_kernel(const float* __restrict__ query,
                                                 const float* __restrict__ W_s,
                                                 float* __restrict__ qs) {
    const int b = blockIdx.x, k = threadIdx.x;
    __shared__ float q[H];
    q[k] = query[b * H + k];
    __syncthreads();
    float acc = 0.f;
#pragma unroll 8
    for (int h = 0; h < H; ++h) acc = fmaf(q[h], W_s[h * H + k], acc);
    qs[b * H + k] = acc;
}

// -------- kernel 1b: W_h -> bf16 step-major fragment-ordered Wt --------
// layout: [step 16][wc 4][cb 8][lane 64][j 8] shorts
// element = W_h[k][col], k = step*32 + (lane>>4)*8 + j, col = wc*128 + cb*16 + (lane&15)
__global__ __launch_bounds__(256) void wt_prep(const float* __restrict__ W_h,
                                               short* __restrict__ Wt) {
    const int idx = blockIdx.x * 256 + threadIdx.x;       // 0 .. 262143
    const int j  = idx & 7;
    const int l  = (idx >> 3) & 63;
    const int cb = (idx >> 9) & 7;
    const int wc = (idx >> 12) & 3;
    const int st = idx >> 14;
    const int k   = st * 32 + (l >> 4) * 8 + j;
    const int col = wc * 128 + cb * 16 + (l & 15);
    Wt[idx] = f2bf(W_h[k * H + col]);
}

// ------- kernel 2: scores = v.tanh(enc@W_h + qs) — counted-vmcnt pipeline (T3/T4) -------
// 1024 blocks (64 b x 16 row-tiles of 128), 512 thr = 8 waves (2 row-grp x 4 col-grp).
// Per iter: issue B(st+2) GLL + A(st+2) reg loads; MFMA on st (pre-guaranteed);
// vmcnt(6) retires B(st+1)+A(st+1) BEFORE the barrier (race-safe), 6 ops stay in flight.
__global__ __launch_bounds__(512, 2) void scores_mfma_kernel(const float* __restrict__ enc,
                                                             const short* __restrict__ Wt,
                                                             const float* __restrict__ v,
                                                             const int* __restrict__ lens,
                                                             const float* __restrict__ qs,
                                                             float* __restrict__ scores) {
    const int b  = blockIdx.x >> 4;
    const int s0 = (blockIdx.x & 15) * BMT;
    const int len = lens[b];
    if (s0 >= len) return;

    const int t = threadIdx.x;
    const int w = t >> 6, l = t & 63;
    const int wr = w >> 2, wc = w & 3;
    const int g = l >> 4, c = l & 15;

    __shared__ __attribute__((aligned(16))) char Bs[3][32768];  // B: 3-buf, 32k x 512 cols bf16
    __shared__ __attribute__((aligned(16))) char As[2][9216];   // A: 2-buf, 128 rows x 72 B
    __shared__ float red[4][BMT];

    // A staging: thread t -> row t>>2 (128 rows), slot t&3 (8 floats = 32 B)
    const int arow = t >> 2, aslot = t & 3;
    const float* agA = enc + ((size_t)(b * S + s0 + arow)) * H + aslot * 8;
    const char* WtB = (const char*)Wt;

    float4 Aa0, Aa1, Ab0, Ab1;

#define STAGE_B(st_, bf_)                                                      \
    {                                                                          \
        const char* gs_ = WtB + (size_t)(st_) * 32768 + w * 4096 + (size_t)l * 16; \
        char* ls_ = &Bs[(bf_)][w * 4096];                                      \
        GLL16(gs_,        ls_);                                                \
        GLL16(gs_ + 1024, ls_ + 1024);                                         \
        GLL16(gs_ + 2048, ls_ + 2048);                                         \
        GLL16(gs_ + 3072, ls_ + 3072);                                         \
    }

#define LOADA(d0_, d1_, st_)                                                   \
    { const float4* p_ = (const float4*)(agA + (st_) * 32); d0_ = p_[0]; d1_ = p_[1]; }

#define WRITEA(s0_, s1_, bf_)                                                  \
    *(short8*)(&As[(bf_)][0] + arow * 72 + aslot * 16) = cvt8(s0_, s1_);

#define VMW(n_)                                                                \
    asm volatile("s_waitcnt vmcnt(" n_ ")" ::: "memory");                      \
    __builtin_amdgcn_sched_barrier(0);

#define BARRIER()                                                              \
    asm volatile("s_waitcnt lgkmcnt(0)" ::: "memory");                         \
    __builtin_amdgcn_s_barrier();

#define COMPUTE(st_)                                                           \
    {                                                                          \
        const char* ab_ = &As[(st_) & 1][0] + (wr * 64 + c) * 72 + g * 16;     \
        const char* bb_ = &Bs[(st_) % 3][wc * 8192] + l * 16;                  \
        const short8 af0 = *(const short8*)(ab_);                              \
        const short8 af1 = *(const short8*)(ab_ + 16 * 72);                    \
        const short8 af2 = *(const short8*)(ab_ + 32 * 72);                    \
        const short8 af3 = *(const short8*)(ab_ + 48 * 72);                    \
        __builtin_amdgcn_s_setprio(1);                                         \
        _Pragma("unroll")                                                      \
        for (int cb = 0; cb < 8; ++cb) {                                       \
            const short8 bf = *(const short8*)(bb_ + cb * 1024);               \
            acc[0][cb] = __builtin_amdgcn_mfma_f32_16x16x32_bf16(af0, bf, acc[0][cb], 0, 0, 0); \
            acc[1][cb] = __builtin_amdgcn_mfma_f32_16x16x32_bf16(af1, bf, acc[1][cb], 0, 0, 0); \
            acc[2][cb] = __builtin_amdgcn_mfma_f32_16x16x32_bf16(af2, bf, acc[2][cb], 0, 0, 0); \
            acc[3][cb] = __builtin_amdgcn_mfma_f32_16x16x32_bf16(af3, bf, acc[3][cb], 0, 0, 0); \
        }                                                                      \
        __builtin_amdgcn_s_setprio(0);                                         \
    }

// steady-state iter: issue (st+2), compute (st), retire (st+1), write A(st+1), barrier
#define STEP(st_, AC0, AC1, AN0, AN1)                                          \
    {                                                                          \
        STAGE_B((st_) + 2, ((st_) + 2) % 3)                                    \
        LOADA(AN0, AN1, (st_) + 2)                                             \
        COMPUTE(st_)                                                           \
        VMW("6")                                                               \
        WRITEA(AC0, AC1, ((st_) + 1) & 1)                                      \
        BARRIER()                                                              \
    }

    f32x4 acc[4][8];
    const f32x4 z = {0.f, 0.f, 0.f, 0.f};
#pragma unroll
    for (int rb = 0; rb < 4; ++rb)
#pragma unroll
        for (int cb = 0; cb < 8; ++cb) acc[rb][cb] = z;

    // prologue — issue order matters for vmcnt counting: B0(4), A0(2), B1(4), A1(2)
    STAGE_B(0, 0)
    LOADA(Aa0, Aa1, 0)
    STAGE_B(1, 1)
    LOADA(Ab0, Ab1, 1)
    VMW("6")                       // retire B0 + A0; B1 + A1 stay in flight
    WRITEA(Aa0, Aa1, 0)
    BARRIER()

    STEP(0,  Ab0, Ab1, Aa0, Aa1)   // consume A1, load A2
    STEP(1,  Aa0, Aa1, Ab0, Ab1)
    STEP(2,  Ab0, Ab1, Aa0, Aa1)
    STEP(3,  Aa0, Aa1, Ab0, Ab1)
    STEP(4,  Ab0, Ab1, Aa0, Aa1)
    STEP(5,  Aa0, Aa1, Ab0, Ab1)
    STEP(6,  Ab0, Ab1, Aa0, Aa1)
    STEP(7,  Aa0, Aa1, Ab0, Ab1)
    STEP(8,  Ab0, Ab1, Aa0, Aa1)
    STEP(9,  Aa0, Aa1, Ab0, Ab1)
    STEP(10, Ab0, Ab1, Aa0, Aa1)
    STEP(11, Aa0, Aa1, Ab0, Ab1)
    STEP(12, Ab0, Ab1, Aa0, Aa1)
    STEP(13, Aa0, Aa1, Ab0, Ab1)
    // iter 14: nothing left to issue; retire everything, write A(15)
    COMPUTE(14)
    VMW("0")
    WRITEA(Ab0, Ab1, 1)
    BARRIER()
    // iter 15
    COMPUTE(15)

    // ---- epilogue: p[row] = sum_col v[col] * tanh(escore + qs[col]) ----
    float vreg[8], qreg[8];
#pragma unroll
    for (int cb = 0; cb < 8; ++cb) {
        vreg[cb] = v[wc * 128 + cb * 16 + c];
        qreg[cb] = qs[b * H + wc * 128 + cb * 16 + c];
    }

    float part[4][4];
#pragma unroll
    for (int rb = 0; rb < 4; ++rb)
#pragma unroll
        for (int r = 0; r < 4; ++r) part[rb][r] = 0.f;

#pragma unroll
    for (int cb = 0; cb < 8; ++cb)
#pragma unroll
        for (int rb = 0; rb < 4; ++rb)
#pragma unroll
            for (int r = 0; r < 4; ++r)
                part[rb][r] += vreg[cb] * ftanh(acc[rb][cb][r] + qreg[cb]);
#pragma unroll
    for (int m = 1; m < 16; m <<= 1)
#pragma unroll
        for (int rb = 0; rb < 4; ++rb)
#pragma unroll
            for (int r = 0; r < 4; ++r)
                part[rb][r] += __shfl_xor(part[rb][r], m);
    if (c == 0) {
#pragma unroll
        for (int rb = 0; rb < 4; ++rb)
#pragma unroll
            for (int r = 0; r < 4; ++r)
                red[wc][wr * 64 + rb * 16 + g * 4 + r] = part[rb][r];
    }
    __syncthreads();
    if (t < BMT)
        scores[b * S + s0 + t] = red[0][t] + red[1][t] + red[2][t] + red[3][t];
#undef STAGE_B
#undef LOADA
#undef WRITEA
#undef VMW
#undef BARRIER
#undef COMPUTE
#undef STEP
}

// ---------------- kernel 3: masked softmax over S, write attn ----------------
__global__ __launch_bounds__(256) void softmax_kernel(const float* __restrict__ scores,
                                                      const int* __restrict__ lens,
                                                      float* __restrict__ attn) {
    const int b = blockIdx.x, t = threadIdx.x;
    const int len = lens[b];
    const int wave = t >> 6, lane = t & 63;
    __shared__ float red[4];

    float vals[8];
    float m = -INFINITY;
#pragma unroll
    for (int i = 0; i < 8; ++i) {
        const int s = i * 256 + t;
        vals[i] = (s < len) ? scores[b * S + s] : -INFINITY;
        m = fmaxf(m, vals[i]);
    }
#pragma unroll
    for (int off = 32; off > 0; off >>= 1) m = fmaxf(m, __shfl_down(m, off));
    if (lane == 0) red[wave] = m;
    __syncthreads();
    m = fmaxf(fmaxf(red[0], red[1]), fmaxf(red[2], red[3]));
    __syncthreads();

    float e[8];
    float sum = 0.f;
#pragma unroll
    for (int i = 0; i < 8; ++i) {
        const int s = i * 256 + t;
        e[i] = (s < len) ? expf(vals[i] - m) : 0.f;
        sum += e[i];
    }
#pragma unroll
    for (int off = 32; off > 0; off >>= 1) sum += __shfl_down(sum, off);
    if (lane == 0) red[wave] = sum;
    __syncthreads();
    const float inv = 1.f / (red[0] + red[1] + red[2] + red[3]);
#pragma unroll
    for (int i = 0; i < 8; ++i) attn[b * S + i * 256 + t] = e[i] * inv;
}

// -------- kernel 4a: partial context sums over s-chunks (masked skipped) --------
__global__ __launch_bounds__(256) void ctx_partial_kernel(const float* __restrict__ enc,
                                                          const float* __restrict__ attn,
                                                          const int* __restrict__ lens,
                                                          float* __restrict__ pc) {
    const int b = blockIdx.x >> 5, c = blockIdx.x & 31;
    const int len = lens[b];
    const int sbase = c * CHUNK;
    if (sbase >= len) return;
    const int ns = min(CHUNK, len - sbase);
    const int t = threadIdx.x;

    __shared__ float alds[CHUNK];
    if (t < CHUNK) alds[t] = (t < ns) ? attn[b * S + sbase + t] : 0.f;
    __syncthreads();

    const float2* e2 = (const float2*)(enc + (size_t)(b * S + sbase) * H);
    float2 acc = make_float2(0.f, 0.f);
    for (int s = 0; s < ns; ++s) {
        const float a = alds[s];
        const float2 e = e2[s * 256 + t];
        acc.x = fmaf(a, e.x, acc.x);
        acc.y = fmaf(a, e.y, acc.y);
    }
    ((float2*)(pc + (size_t)(b * NCHUNK + c) * H))[t] = acc;
}

// ------ kernel 4b: context reduce + w_out = tanh([ctx, q] @ W_out) ------
__global__ __launch_bounds__(512) void out_kernel(const float* __restrict__ pc,
                                                  const float* __restrict__ query,
                                                  const float* __restrict__ W_out,
                                                  const int* __restrict__ lens,
                                                  float* __restrict__ wout) {
    const int b = blockIdx.x, k = threadIdx.x;
    const int len = lens[b];
    const int nch = (len + CHUNK - 1) / CHUNK;
    __shared__ float cat[2 * H];
    float ctx = 0.f;
    for (int c = 0; c < nch; ++c) ctx += pc[(size_t)(b * NCHUNK + c) * H + k];
    cat[k] = ctx;
    cat[H + k] = query[b * H + k];
    __syncthreads();
    float acc = 0.f;
#pragma unroll 8
    for (int c = 0; c < 2 * H; ++c) acc = fmaf(cat[c], W_out[c * H + k], acc);
    wout[b * H + k] = tanhf(acc);
}

extern "C" void kernel_launch(void* const* d_in, const int* in_sizes, int n_in,
                              void* d_out, int out_size, void* d_ws, size_t ws_size,
                              hipStream_t stream) {
    const float* query = (const float*)d_in[0];
    const float* enc   = (const float*)d_in[1];
    const int*   lens  = (const int*)d_in[2];
    const float* W_h   = (const float*)d_in[3];
    const float* W_s   = (const float*)d_in[4];
    const float* v     = (const float*)d_in[5];
    const float* W_out = (const float*)d_in[6];

    float* out  = (float*)d_out;
    float* wout = out;          // B*H
    float* attn = out + B * H;  // B*S

    float* ws     = (float*)d_ws;
    float* qs     = ws + QS_OFF;
    float* scores = ws + SC_OFF;
    float* pc     = ws + PC_OFF;
    short* Wt     = (short*)(ws + PC_OFF);   // aliases pc: Wt used in scores (before pc written)

    qs_kernel<<<B, H, 0, stream>>>(query, W_s, qs);
    wt_prep<<<1024, 256, 0, stream>>>(W_h, Wt);
    scores_mfma_kernel<<<B * (S / BMT), 512, 0, stream>>>(enc, Wt, v, lens, qs, scores);
    softmax_kernel<<<B, 256, 0, stream>>>(scores, lens, attn);
    ctx_partial_kernel<<<B * NCHUNK, 256, 0, stream>>>(enc, attn, lens, pc);
    out_kernel<<<B, H, 0, stream>>>(pc, query, W_out, lens, wout);
}